// Round 4
// baseline (53.177 us; speedup 1.0000x reference)
//
#include <hip/hip_runtime.h>
#include <hip/hip_bf16.h>

// Problem constants (match reference)
#define MB 4096      // B rows
#define MD 4096      // D classes
#define MP 8         // P positives per row
#define MARGIN 0.5f
#define ROWS 4       // rows per block
#define NB (MB / ROWS)   // 1024 blocks

typedef float f32x4 __attribute__((ext_vector_type(4)));

// Fused single kernel. Each block handles ROWS rows:
//   partial = sum_{rows} [ sum_{all d} sum_k relu(M + x[d] - x[pos_k])
//                          - sum_{distinct pos d} sum_k relu(M + x[d] - x[pos_k]) ]
// The unconditional column sum needs no masking (3 VALU ops/hinge); the
// positive-column correction depends only on the 8 anchors and is folded into
// lanes 0..7's accumulators (no serial t0 work).
// Block partial -> ws; last block (device-scope ticket) reduces all partials
// and writes out[0]. Deterministic: one block sums in fixed order.
__global__ __launch_bounds__(256) void margin_fused_kernel(
    const float* __restrict__ x,
    const int* __restrict__ pos_ids,
    float* __restrict__ partials,   // NB floats
    int* __restrict__ counter,      // memset to 0 each launch
    float* __restrict__ out)
{
    const int t = threadIdx.x;
    const int lane = t & 63;
    const int wave = t >> 6;
    const int row0 = blockIdx.x * ROWS;

    float acc0 = 0.0f, acc1 = 0.0f;   // two chains for ILP

#pragma unroll
    for (int r = 0; r < ROWS; ++r) {
        const int row = row0 + r;
        const float* __restrict__ xr = x + (size_t)row * MD;

        // dependency chain first: pos_ids -> gather -> shfl broadcast
        const int p = pos_ids[row * MP + (lane & 7)];

        // independent streaming loads, issued early
        const f32x4* __restrict__ xr4 = reinterpret_cast<const f32x4*>(xr);
        const f32x4 v0 = __builtin_nontemporal_load(xr4 + t);
        const f32x4 v1 = __builtin_nontemporal_load(xr4 + 256 + t);
        const f32x4 v2 = __builtin_nontemporal_load(xr4 + 512 + t);
        const f32x4 v3 = __builtin_nontemporal_load(xr4 + 768 + t);

        const float xg = xr[p];   // 8 unique addresses per wave (cache hits)

        float th[MP];
        int   pi[MP];
#pragma unroll
        for (int k = 0; k < MP; ++k) {
            th[k] = __shfl(xg, k, 64) - MARGIN;
            pi[k] = __shfl(p, k, 64);
        }

        const float vv[16] = { v0.x, v0.y, v0.z, v0.w,
                               v1.x, v1.y, v1.z, v1.w,
                               v2.x, v2.y, v2.z, v2.w,
                               v3.x, v3.y, v3.z, v3.w };

#pragma unroll
        for (int j = 0; j < 16; ++j) {
            const float v = vv[j];
#pragma unroll
            for (int k = 0; k < MP; k += 2) {
                acc0 += fmaxf(0.0f, v - th[k]);
                acc1 += fmaxf(0.0f, v - th[k + 1]);
            }
        }

        // Positive-column correction: lane l (<8) of wave 0 subtracts the
        // contribution of anchor column pos[l] (dedup duplicates, since
        // y[i,d]=1 no matter how often d repeats in pos_ids).
        if (t < MP) {
            bool dup = false;
#pragma unroll
            for (int k2 = 0; k2 < MP; ++k2) dup = dup || (k2 < t && pi[k2] == pi[t]);
            if (!dup) {
                const float xk = th[t] + MARGIN;   // = x[row, pos_t]
#pragma unroll
                for (int j = 0; j < MP; ++j)
                    acc0 -= fmaxf(0.0f, xk - th[j]);
            }
        }
    }

    float acc = acc0 + acc1;
#pragma unroll
    for (int off = 32; off > 0; off >>= 1)
        acc += __shfl_down(acc, off, 64);

    __shared__ float s_part[4];
    __shared__ int s_last;
    if ((t & 63) == 0) s_part[wave] = acc;
    __syncthreads();

    if (t == 0) {
        const float bp = s_part[0] + s_part[1] + s_part[2] + s_part[3];
        __hip_atomic_store(&partials[blockIdx.x], bp,
                           __ATOMIC_RELAXED, __HIP_MEMORY_SCOPE_AGENT);
        const int ticket = __hip_atomic_fetch_add(counter, 1,
                           __ATOMIC_ACQ_REL, __HIP_MEMORY_SCOPE_AGENT);
        s_last = (ticket == NB - 1);
    }
    __syncthreads();

    if (s_last) {
        // last block: reduce all NB partials (coherent agent-scope loads)
        double d = 0.0;
#pragma unroll
        for (int it = 0; it < NB / 256; ++it)
            d += (double)__hip_atomic_load(&partials[it * 256 + t],
                         __ATOMIC_RELAXED, __HIP_MEMORY_SCOPE_AGENT);
#pragma unroll
        for (int off = 32; off > 0; off >>= 1)
            d += __shfl_down(d, off, 64);

        __shared__ double s_d[4];
        if ((t & 63) == 0) s_d[wave] = d;
        __syncthreads();
        if (t == 0) {
            const double tot = s_d[0] + s_d[1] + s_d[2] + s_d[3];
            const double count = (double)MB * (double)MP * (double)(MD - MP);
            out[0] = (float)(tot / count);
        }
    }
}

extern "C" void kernel_launch(void* const* d_in, const int* in_sizes, int n_in,
                              void* d_out, int out_size, void* d_ws, size_t ws_size,
                              hipStream_t stream) {
    const float* x = (const float*)d_in[0];
    // d_in[1] is y, redundant with pos_ids — not read (halves HBM traffic).
    const int* pos_ids = (const int*)d_in[2];
    float* out = (float*)d_out;

    int* counter = (int*)d_ws;                          // 1 int, own cacheline
    float* partials = (float*)((char*)d_ws + 256);      // NB floats

    hipMemsetAsync(counter, 0, sizeof(int), stream);
    margin_fused_kernel<<<NB, 256, 0, stream>>>(x, pos_ids, partials, counter, out);
}